// Round 1
// baseline (2846.793 us; speedup 1.0000x reference)
//
#include <hip/hip_runtime.h>

#define BB 256
#define TT 1024
#define II 128
#define GG 512   // 2C
#define CC 256

typedef _Float16 f16;
typedef _Float16 h2_t __attribute__((ext_vector_type(2)));
typedef _Float16 h8_t __attribute__((ext_vector_type(8)));
typedef float f4_t __attribute__((ext_vector_type(4)));

static __device__ __forceinline__ float fdot2f(h2_t a, h2_t b, float c) {
#if __has_builtin(__builtin_amdgcn_fdot2)
    return __builtin_amdgcn_fdot2(a, b, c, false);
#else
    return c + (float)a[0] * (float)b[0] + (float)a[1] * (float)b[1];
#endif
}

// ---- kernel 1: Kt[n][k] = f16(kernel[k][n])  (128x512 -> 512x128) ----
__global__ void kt_transpose(const float* __restrict__ kin, f16* __restrict__ kt) {
    int idx = blockIdx.x * 256 + threadIdx.x;   // 65536 total
    int k = idx >> 9;       // coalesced read (n fast-varying)
    int n = idx & 511;
    kt[n * II + k] = (f16)kin[k * GG + n];
}

// ---- kernel 2: xz = f16(x @ K + bias), [M=262144][512], MFMA f16 16x16x32 ----
__global__ __launch_bounds__(256)
void gemm_xz(const float* __restrict__ x, const f16* __restrict__ kt,
             const float* __restrict__ bias, unsigned short* __restrict__ xz) {
    const int  ntile = blockIdx.x;   // 0..3   (128 cols each)
    const long mtile = blockIdx.y;   // 0..2047 (128 rows each)
    const int wave = threadIdx.x >> 6;
    const int lane = threadIdx.x & 63;
    const int wm = (wave & 1) * 64;
    const int wn = (wave >> 1) * 64;
    const int lm = lane & 15;
    const int q  = lane >> 4;

    f4_t acc[4][4];
#pragma unroll
    for (int mi = 0; mi < 4; ++mi)
#pragma unroll
        for (int ni = 0; ni < 4; ++ni)
            acc[mi][ni] = (f4_t){0.f, 0.f, 0.f, 0.f};

#pragma unroll
    for (int kc = 0; kc < 4; ++kc) {
        h8_t a[4], bf[4];
#pragma unroll
        for (int mi = 0; mi < 4; ++mi) {
            const float* ap = x + ((size_t)(mtile * 128 + wm + mi * 16 + lm)) * II + kc * 32 + q * 8;
            f4_t p0 = *(const f4_t*)ap;
            f4_t p1 = *(const f4_t*)(ap + 4);
            h8_t tv;
            tv[0] = (f16)p0[0]; tv[1] = (f16)p0[1]; tv[2] = (f16)p0[2]; tv[3] = (f16)p0[3];
            tv[4] = (f16)p1[0]; tv[5] = (f16)p1[1]; tv[6] = (f16)p1[2]; tv[7] = (f16)p1[3];
            a[mi] = tv;
        }
#pragma unroll
        for (int ni = 0; ni < 4; ++ni) {
            const f16* bp = kt + (size_t)(ntile * 128 + wn + ni * 16 + lm) * II + kc * 32 + q * 8;
            bf[ni] = *(const h8_t*)bp;
        }
#pragma unroll
        for (int mi = 0; mi < 4; ++mi)
#pragma unroll
            for (int ni = 0; ni < 4; ++ni)
                acc[mi][ni] = __builtin_amdgcn_mfma_f32_16x16x32_f16(a[mi], bf[ni], acc[mi][ni], 0, 0, 0);
    }

    // epilogue: C/D layout col=lane&15, row=(lane>>4)*4+reg  (m89-verified)
#pragma unroll
    for (int mi = 0; mi < 4; ++mi) {
#pragma unroll
        for (int ni = 0; ni < 4; ++ni) {
            const int col = ntile * 128 + wn + ni * 16 + lm;
            const float bv = bias[col];
#pragma unroll
            for (int r = 0; r < 4; ++r) {
                const size_t row = (size_t)(mtile * 128 + wm + mi * 16 + q * 4 + r);
                f16 hv = (f16)(acc[mi][ni][r] + bv);
                xz[row * GG + col] = *(unsigned short*)&hv;
            }
        }
    }
}

// ---- kernel 3: the serial recurrence, one WG per batch ----
// thread g in [0,512) owns gate g; W[:,g] resident as 128 packed f16 pairs.
// h (=c) round-trips through the consumed xz[b][t][0:256] slot as f16 so the
// matvec operand is a uniform-address load (broadcast), not per-lane LDS reads.
__global__ __launch_bounds__(512, 2)
void janet_rec(const float* __restrict__ rk, const float* __restrict__ dw,
               const float* __restrict__ db, unsigned short* __restrict__ xz,
               float* __restrict__ out) {
    const int b = blockIdx.x;
    const int g = threadIdx.x;

    h2_t w[128];
#pragma unroll
    for (int p = 0; p < 128; ++p) {
        float w0 = rk[(2 * p + 0) * GG + g];
        float w1 = rk[(2 * p + 1) * GG + g];
        h2_t tv; tv[0] = (f16)w0; tv[1] = (f16)w1;
        w[p] = tv;
    }

    __shared__ float cand[CC];
    __shared__ float hfin[CC];

    float c = 0.f;
    unsigned short* row = xz + (size_t)b * TT * GG;

#pragma unroll 1
    for (int t = 0; t < TT; ++t) {
        unsigned short zx16 = row[t * GG + g];
        f16 zxh = *(f16*)&zx16;
        float zv = (float)zxh;
        if (t > 0) {
            const uint4* hp = (const uint4*)(row + (t - 1) * GG);  // uniform address
            float acc0 = 0.f, acc1 = 0.f;
#pragma unroll
            for (int cc = 0; cc < 32; ++cc) {
                uint4 hv = hp[cc];
                acc0 = fdot2f(w[4 * cc + 0], __builtin_bit_cast(h2_t, hv.x), acc0);
                acc1 = fdot2f(w[4 * cc + 1], __builtin_bit_cast(h2_t, hv.y), acc1);
                acc0 = fdot2f(w[4 * cc + 2], __builtin_bit_cast(h2_t, hv.z), acc0);
                acc1 = fdot2f(w[4 * cc + 3], __builtin_bit_cast(h2_t, hv.w), acc1);
            }
            zv += acc0 + acc1;
        }
        if (g >= CC) {
            // tanh without overflow: tanh(|z|) = (1-e^{-2|z|})/(1+e^{-2|z|})
            float az = fabsf(zv);
            float e = __expf(-2.f * az);
            float th = (1.f - e) / (1.f + e);
            cand[g - CC] = copysignf(th, zv);
        }
        __syncthreads();
        if (g < CC) {
            float f = 1.f / (1.f + __expf(-zv));
            c = f * c + (1.f - f) * cand[g];
            f16 hc = (f16)c;                      // cell state stays fp32 in reg;
            row[t * GG + g] = *(unsigned short*)&hc;  // only the matvec copy is f16
        }
        __syncthreads();   // implies vmcnt drain -> stores visible to next-step loads
    }

    if (g < CC) hfin[g] = c;
    __syncthreads();
    if (g < 10) {
        float acc = db[g];
#pragma unroll 8
        for (int cc = 0; cc < CC; ++cc) acc += hfin[cc] * dw[cc * 10 + g];
        out[b * 10 + g] = acc;
    }
}

// ---- guard: if ws too small, fail cleanly and leak ws_size via out[0] ----
__global__ void ws_too_small(float* out, float wssz) {
    int i = blockIdx.x * 256 + threadIdx.x;
    if (i < BB * 10) out[i] = (i == 0) ? wssz : 0.f;
}

extern "C" void kernel_launch(void* const* d_in, const int* in_sizes, int n_in,
                              void* d_out, int out_size, void* d_ws, size_t ws_size,
                              hipStream_t stream) {
    const float* x   = (const float*)d_in[0];
    const float* kin = (const float*)d_in[1];
    const float* rk  = (const float*)d_in[2];
    const float* rb  = (const float*)d_in[3];
    const float* dw  = (const float*)d_in[4];
    const float* db  = (const float*)d_in[5];
    float* out = (float*)d_out;

    const size_t xz_bytes = (size_t)BB * TT * GG * 2;   // 268,435,456
    const size_t kt_bytes = (size_t)GG * II * 2;        // 131,072
    if (ws_size < xz_bytes + kt_bytes) {
        ws_too_small<<<10, 256, 0, stream>>>(out, (float)ws_size);
        return;
    }

    unsigned short* xz = (unsigned short*)d_ws;
    f16* kt = (f16*)((char*)d_ws + xz_bytes);

    kt_transpose<<<256, 256, 0, stream>>>(kin, kt);
    gemm_xz<<<dim3(4, 2048), 256, 0, stream>>>(x, kt, rb, xz);
    janet_rec<<<256, 512, 0, stream>>>(rk, dw, db, xz, out);
}

// Round 2
// 2091.904 us; speedup vs baseline: 1.3609x; 1.3609x over previous
//
#include <hip/hip_runtime.h>

#define BB 256
#define TT 1024
#define II 128
#define GG 512   // 2C
#define CC 256

typedef _Float16 f16;
typedef _Float16 h8_t __attribute__((ext_vector_type(8)));
typedef float f4_t __attribute__((ext_vector_type(4)));
typedef unsigned short ushort_t;

static __device__ __forceinline__ float fast_rcp(float x) {
#if __has_builtin(__builtin_amdgcn_rcpf)
    return __builtin_amdgcn_rcpf(x);
#else
    return 1.f / x;
#endif
}

// ---- kernel 1: Kt[n][k] = f16(kernel[k][n])  (128x512 -> 512x128) ----
__global__ void kt_transpose(const float* __restrict__ kin, f16* __restrict__ kt) {
    int idx = blockIdx.x * 256 + threadIdx.x;   // 65536 total
    int k = idx >> 9;
    int n = idx & 511;
    kt[n * II + k] = (f16)kin[k * GG + n];
}

// ---- kernel 2: xz = f16(x @ K + bias), written in recurrence frag-linear order ----
// xz2 index for (batch b, time t, col): g=b>>4, brow=b&15, nt=col>>4, lm=col&15
//   off = ((t*16+g)*8 + (nt&7))*1024 + ((nt>>3)*4 + (brow&3))*64 + (brow>>2)*16 + lm
__global__ __launch_bounds__(256)
void gemm_xz(const float* __restrict__ x, const f16* __restrict__ kt,
             const float* __restrict__ bias, ushort_t* __restrict__ xz2) {
    const int  ntile = blockIdx.x;   // 0..3   (128 cols)
    const long mtile = blockIdx.y;   // 0..2047 (128 rows)
    const int wave = threadIdx.x >> 6;
    const int lane = threadIdx.x & 63;
    const int wm = (wave & 1) * 64;
    const int wn = (wave >> 1) * 64;
    const int lm = lane & 15;
    const int q  = lane >> 4;

    f4_t acc[4][4];
#pragma unroll
    for (int mi = 0; mi < 4; ++mi)
#pragma unroll
        for (int ni = 0; ni < 4; ++ni)
            acc[mi][ni] = (f4_t){0.f, 0.f, 0.f, 0.f};

#pragma unroll
    for (int kc = 0; kc < 4; ++kc) {
        h8_t a[4], bf[4];
#pragma unroll
        for (int mi = 0; mi < 4; ++mi) {
            const float* ap = x + ((size_t)(mtile * 128 + wm + mi * 16 + lm)) * II + kc * 32 + q * 8;
            f4_t p0 = *(const f4_t*)ap;
            f4_t p1 = *(const f4_t*)(ap + 4);
            h8_t tv;
            tv[0] = (f16)p0[0]; tv[1] = (f16)p0[1]; tv[2] = (f16)p0[2]; tv[3] = (f16)p0[3];
            tv[4] = (f16)p1[0]; tv[5] = (f16)p1[1]; tv[6] = (f16)p1[2]; tv[7] = (f16)p1[3];
            a[mi] = tv;
        }
#pragma unroll
        for (int ni = 0; ni < 4; ++ni) {
            const f16* bp = kt + (size_t)(ntile * 128 + wn + ni * 16 + lm) * II + kc * 32 + q * 8;
            bf[ni] = *(const h8_t*)bp;
        }
#pragma unroll
        for (int mi = 0; mi < 4; ++mi)
#pragma unroll
            for (int ni = 0; ni < 4; ++ni)
                acc[mi][ni] = __builtin_amdgcn_mfma_f32_16x16x32_f16(a[mi], bf[ni], acc[mi][ni], 0, 0, 0);
    }

    // epilogue: C/D layout col=lane&15, row=(lane>>4)*4+reg (m89) -> frag-linear store
#pragma unroll
    for (int mi = 0; mi < 4; ++mi) {
#pragma unroll
        for (int ni = 0; ni < 4; ++ni) {
            const int col = ntile * 128 + wn + ni * 16 + lm;
            const float bv = bias[col];
            const int wc  = (col >> 4) & 7;
            const int nic = col >> 7;
            const int lmc = col & 15;
#pragma unroll
            for (int r = 0; r < 4; ++r) {
                const size_t m = (size_t)(mtile * 128 + wm + mi * 16 + q * 4 + r);
                const int b = (int)(m >> 10);
                const int t = (int)(m & 1023);
                const int grp  = b >> 4;
                const int brow = b & 15;
                const size_t off = (((size_t)t * 16 + grp) * 8 + wc) * 1024
                                 + (size_t)((nic * 4 + (brow & 3)) * 64 + (brow >> 2) * 16 + lmc);
                f16 hv = (f16)(acc[mi][ni][r] + bv);
                xz2[off] = *(ushort_t*)&hv;
            }
        }
    }
}

// ---- kernel 3: MFMA recurrence. 16 WGs x 512 thr, 16 batches per WG. ----
// Wave w owns n-tiles {w, w+8, w+16, w+24}. R resident: bw[4][8] h8_t = 128 VGPR.
// h ping-pongs through double-buffered LDS (f16, A-layout, row stride 264).
// xz prefetched 2 steps ahead (16 coalesced 128B loads/step).
#define STEP(T, PF, HRD, HWR) do {                                                   \
    h8_t af[8];                                                                      \
    _Pragma("unroll") for (int kt = 0; kt < 8; ++kt)                                 \
        af[kt] = *(const h8_t*)((HRD) + lm * 264 + kt * 32 + q * 8);                 \
    f4_t acc[4];                                                                     \
    _Pragma("unroll") for (int ni = 0; ni < 4; ++ni) {                               \
        f4_t av;                                                                     \
        _Pragma("unroll") for (int r = 0; r < 4; ++r) {                              \
            ushort_t u = (PF)[ni * 4 + r];                                           \
            f16 hv = *(f16*)&u;                                                      \
            av[r] = (float)hv;                                                       \
        }                                                                            \
        acc[ni] = av;                                                                \
    }                                                                                \
    if ((T) + 2 < TT) {                                                              \
        const ushort_t* pp = xz2 + (((size_t)((T) + 2) * 16 + g) * 8 + wave) * 1024 + lane; \
        _Pragma("unroll") for (int i = 0; i < 16; ++i) (PF)[i] = pp[i * 64];         \
    }                                                                                \
    _Pragma("unroll") for (int kt = 0; kt < 8; ++kt)                                 \
        _Pragma("unroll") for (int ni = 0; ni < 4; ++ni)                             \
            acc[ni] = __builtin_amdgcn_mfma_f32_16x16x32_f16(af[kt], bw[ni][kt], acc[ni], 0, 0, 0); \
    _Pragma("unroll") for (int ni = 0; ni < 2; ++ni)                                 \
        _Pragma("unroll") for (int r = 0; r < 4; ++r) {                              \
            float zf = acc[ni][r];                                                   \
            float zg = acc[ni + 2][r];                                               \
            float ef = __expf(-zf);                                                  \
            float eg = __expf(-2.f * fabsf(zg));                                     \
            float t1 = (zg < 0.f) ? -ef : ef;                                        \
            float cv = cst[ni][r];                                                   \
            float num = fmaf(cv, eg, cv) + fmaf(-t1, eg, t1);                        \
            float den = (1.f + ef) * (1.f + eg);                                     \
            cst[ni][r] = num * fast_rcp(den);                                        \
        }                                                                            \
    _Pragma("unroll") for (int ni = 0; ni < 2; ++ni)                                 \
        _Pragma("unroll") for (int r = 0; r < 4; ++r)                                \
            (HWR)[(q * 4 + r) * 264 + (wave + 8 * ni) * 16 + lm] = (f16)cst[ni][r];  \
    __syncthreads();                                                                 \
} while (0)

__global__ __launch_bounds__(512, 2)
void janet_rec(const float* __restrict__ rk, const float* __restrict__ dw,
               const float* __restrict__ db, const ushort_t* __restrict__ xz2,
               float* __restrict__ out) {
    const int g = blockIdx.x;            // batch group: batches g*16 .. g*16+15
    const int tid = threadIdx.x;
    const int wave = tid >> 6;
    const int lane = tid & 63;
    const int lm = lane & 15;
    const int q  = lane >> 4;

    // resident recurrent weights: bw[ni][kt][j] = R[kt*32+q*8+j][(wave+8*ni)*16+lm]
    h8_t bw[4][8];
#pragma unroll
    for (int ni = 0; ni < 4; ++ni)
#pragma unroll
        for (int kt = 0; kt < 8; ++kt) {
            h8_t tv;
#pragma unroll
            for (int j = 0; j < 8; ++j)
                tv[j] = (f16)rk[(size_t)(kt * 32 + q * 8 + j) * GG + (wave + 8 * ni) * 16 + lm];
            bw[ni][kt] = tv;
        }

    __shared__ __align__(16) f16 hb[2][16][264];   // +8 f16 pad per row
    f16* h0 = &hb[0][0][0];
    f16* h1 = &hb[1][0][0];
    for (int i = tid; i < 16 * 264; i += 512) h0[i] = (f16)0.f;

    float cst[2][4];
#pragma unroll
    for (int ni = 0; ni < 2; ++ni)
#pragma unroll
        for (int r = 0; r < 4; ++r) cst[ni][r] = 0.f;

    // prefetch xz for t=0,1
    ushort_t pf0[16], pf1[16];
    {
        const ushort_t* p0 = xz2 + (((size_t)0 * 16 + g) * 8 + wave) * 1024 + lane;
        const ushort_t* p1 = xz2 + (((size_t)1 * 16 + g) * 8 + wave) * 1024 + lane;
#pragma unroll
        for (int i = 0; i < 16; ++i) { pf0[i] = p0[i * 64]; pf1[i] = p1[i * 64]; }
    }
    __syncthreads();

#pragma unroll 1
    for (int t = 0; t < TT; t += 2) {
        STEP(t,     pf0, h0, h1);
        STEP(t + 1, pf1, h1, h0);
    }

    // final dense: out[b] = h_final @ dense_w + db
    __shared__ float hf[16][256];
#pragma unroll
    for (int ni = 0; ni < 2; ++ni)
#pragma unroll
        for (int r = 0; r < 4; ++r)
            hf[q * 4 + r][(wave + 8 * ni) * 16 + lm] = cst[ni][r];
    __syncthreads();
    if (tid < 160) {
        const int bi = tid / 10, o = tid % 10;
        float acc = db[o];
#pragma unroll 8
        for (int cc = 0; cc < CC; ++cc) acc = fmaf(hf[bi][cc], dw[cc * 10 + o], acc);
        out[(g * 16 + bi) * 10 + o] = acc;
    }
}

// ---- guard ----
__global__ void ws_too_small(float* out, float wssz) {
    int i = blockIdx.x * 256 + threadIdx.x;
    if (i < BB * 10) out[i] = (i == 0) ? wssz : 0.f;
}

extern "C" void kernel_launch(void* const* d_in, const int* in_sizes, int n_in,
                              void* d_out, int out_size, void* d_ws, size_t ws_size,
                              hipStream_t stream) {
    const float* x   = (const float*)d_in[0];
    const float* kin = (const float*)d_in[1];
    const float* rk  = (const float*)d_in[2];
    const float* rb  = (const float*)d_in[3];
    const float* dw  = (const float*)d_in[4];
    const float* db  = (const float*)d_in[5];
    float* out = (float*)d_out;

    const size_t xz_bytes = (size_t)TT * 16 * 8 * 1024 * 2;  // 268,435,456
    const size_t kt_bytes = (size_t)GG * II * 2;             // 131,072
    if (ws_size < xz_bytes + kt_bytes) {
        ws_too_small<<<10, 256, 0, stream>>>(out, (float)ws_size);
        return;
    }

    ushort_t* xz2 = (ushort_t*)d_ws;
    f16* kt = (f16*)((char*)d_ws + xz_bytes);

    kt_transpose<<<256, 256, 0, stream>>>(kin, kt);
    gemm_xz<<<dim3(4, 2048), 256, 0, stream>>>(x, kt, rb, xz2);
    janet_rec<<<16, 512, 0, stream>>>(rk, dw, db, xz2, out);
}

// Round 3
// 1733.395 us; speedup vs baseline: 1.6423x; 1.2068x over previous
//
#include <hip/hip_runtime.h>

#define BB 256
#define TT 1024
#define II 128
#define GG 512   // 2C
#define CC 256

typedef _Float16 f16;
typedef _Float16 h8_t __attribute__((ext_vector_type(8)));
typedef float f4_t __attribute__((ext_vector_type(4)));
typedef unsigned short ushort_t;

static __device__ __forceinline__ float fast_rcp(float x) {
#if __has_builtin(__builtin_amdgcn_rcpf)
    return __builtin_amdgcn_rcpf(x);
#else
    return 1.f / x;
#endif
}

// ---- kernel 1: Kt[n][k] = f16(kernel[k][n])  (128x512 -> 512x128) ----
__global__ void kt_transpose(const float* __restrict__ kin, f16* __restrict__ kt) {
    int idx = blockIdx.x * 256 + threadIdx.x;   // 65536 total
    int k = idx >> 9;
    int n = idx & 511;
    kt[n * II + k] = (f16)kin[k * GG + n];
}

// ---- kernel 2: xz = f16(x @ K + bias), LINEAR layout [B*T][512] (coalesced stores) ----
__global__ __launch_bounds__(256)
void gemm_xz(const float* __restrict__ x, const f16* __restrict__ kt,
             const float* __restrict__ bias, ushort_t* __restrict__ xz) {
    const int  ntile = blockIdx.x;   // 0..3   (128 cols)
    const long mtile = blockIdx.y;   // 0..2047 (128 rows)
    const int wave = threadIdx.x >> 6;
    const int lane = threadIdx.x & 63;
    const int wm = (wave & 1) * 64;
    const int wn = (wave >> 1) * 64;
    const int lm = lane & 15;
    const int q  = lane >> 4;

    f4_t acc[4][4];
#pragma unroll
    for (int mi = 0; mi < 4; ++mi)
#pragma unroll
        for (int ni = 0; ni < 4; ++ni)
            acc[mi][ni] = (f4_t){0.f, 0.f, 0.f, 0.f};

#pragma unroll
    for (int kc = 0; kc < 4; ++kc) {
        h8_t a[4], bf[4];
#pragma unroll
        for (int mi = 0; mi < 4; ++mi) {
            const float* ap = x + ((size_t)(mtile * 128 + wm + mi * 16 + lm)) * II + kc * 32 + q * 8;
            f4_t p0 = *(const f4_t*)ap;
            f4_t p1 = *(const f4_t*)(ap + 4);
            h8_t tv;
            tv[0] = (f16)p0[0]; tv[1] = (f16)p0[1]; tv[2] = (f16)p0[2]; tv[3] = (f16)p0[3];
            tv[4] = (f16)p1[0]; tv[5] = (f16)p1[1]; tv[6] = (f16)p1[2]; tv[7] = (f16)p1[3];
            a[mi] = tv;
        }
#pragma unroll
        for (int ni = 0; ni < 4; ++ni) {
            const f16* bp = kt + (size_t)(ntile * 128 + wn + ni * 16 + lm) * II + kc * 32 + q * 8;
            bf[ni] = *(const h8_t*)bp;
        }
#pragma unroll
        for (int mi = 0; mi < 4; ++mi)
#pragma unroll
            for (int ni = 0; ni < 4; ++ni)
                acc[mi][ni] = __builtin_amdgcn_mfma_f32_16x16x32_f16(a[mi], bf[ni], acc[mi][ni], 0, 0, 0);
    }

    // epilogue: C/D layout col=lane&15, row=(lane>>4)*4+reg (m89-verified), linear store
#pragma unroll
    for (int mi = 0; mi < 4; ++mi) {
#pragma unroll
        for (int ni = 0; ni < 4; ++ni) {
            const int col = ntile * 128 + wn + ni * 16 + lm;
            const float bv = bias[col];
#pragma unroll
            for (int r = 0; r < 4; ++r) {
                const size_t row = (size_t)(mtile * 128 + wm + mi * 16 + q * 4 + r);
                f16 hv = (f16)(acc[mi][ni][r] + bv);
                xz[row * GG + col] = *(ushort_t*)&hv;
            }
        }
    }
}

// ---- kernel 3: MFMA recurrence. 32 WGs x 512 thr, 8 batches per WG (M rows 8..15 zero-pad).
// Wave w owns n-tiles {w, w+8, w+16, w+24}; R resident in bw[4][8] (128 VGPRs).
// h ping-pongs through double-buffered LDS; xz (linear layout) prefetched 2 steps
// ahead as guarded scalar ushort loads. The in-loop barrier is RAW
// (s_waitcnt lgkmcnt(0); s_barrier) so in-flight global prefetch loads are NOT
// drained at the barrier (compiler's __syncthreads would emit vmcnt(0)).
#define STEP(T, PF, HRD, HWR) do {                                                   \
    h8_t af[8];                                                                      \
    _Pragma("unroll") for (int kt = 0; kt < 8; ++kt)                                 \
        af[kt] = *(const h8_t*)((HRD) + lm * 264 + kt * 32 + q * 8);                 \
    f4_t acc[4];                                                                     \
    if (q < 2) {                                                                     \
        _Pragma("unroll") for (int ni = 0; ni < 4; ++ni) {                           \
            f4_t av;                                                                 \
            _Pragma("unroll") for (int r = 0; r < 4; ++r) {                          \
                ushort_t u = (PF)[ni * 4 + r];                                       \
                f16 hv = *(f16*)&u;                                                  \
                av[r] = (float)hv;                                                   \
            }                                                                        \
            acc[ni] = av;                                                            \
        }                                                                            \
    } else {                                                                         \
        _Pragma("unroll") for (int ni = 0; ni < 4; ++ni)                             \
            acc[ni] = (f4_t){0.f, 0.f, 0.f, 0.f};                                    \
    }                                                                                \
    if ((T) + 2 < TT && q < 2) {                                                     \
        _Pragma("unroll") for (int r = 0; r < 4; ++r)                                \
            _Pragma("unroll") for (int ni = 0; ni < 4; ++ni)                         \
                (PF)[ni * 4 + r] = xzb[(size_t)r * 524288 + (size_t)((T) + 2) * 512 + ni * 128]; \
    }                                                                                \
    _Pragma("unroll") for (int kt = 0; kt < 8; ++kt)                                 \
        _Pragma("unroll") for (int ni = 0; ni < 4; ++ni)                             \
            acc[ni] = __builtin_amdgcn_mfma_f32_16x16x32_f16(af[kt], bw[ni][kt], acc[ni], 0, 0, 0); \
    if (q < 2) {                                                                     \
        _Pragma("unroll") for (int ni = 0; ni < 2; ++ni)                             \
            _Pragma("unroll") for (int r = 0; r < 4; ++r) {                          \
                float zf = acc[ni][r];                                               \
                float zg = acc[ni + 2][r];                                           \
                float ef = __expf(-zf);                                              \
                float eg = __expf(-2.f * fabsf(zg));                                 \
                float t1 = (zg < 0.f) ? -ef : ef;                                    \
                float cv = cst[ni][r];                                               \
                float num = fmaf(cv, eg, cv) + fmaf(-t1, eg, t1);                    \
                float den = (1.f + ef) * (1.f + eg);                                 \
                cst[ni][r] = num * fast_rcp(den);                                    \
            }                                                                        \
        _Pragma("unroll") for (int ni = 0; ni < 2; ++ni)                             \
            _Pragma("unroll") for (int r = 0; r < 4; ++r)                            \
                (HWR)[(q * 4 + r) * 264 + (wave + 8 * ni) * 16 + lm] = (f16)cst[ni][r]; \
    }                                                                                \
    asm volatile("s_waitcnt lgkmcnt(0)\n\ts_barrier" ::: "memory");                  \
} while (0)

__global__ __launch_bounds__(512, 2)
void janet_rec(const float* __restrict__ rk, const float* __restrict__ dw,
               const float* __restrict__ db, const ushort_t* __restrict__ xz,
               float* __restrict__ out) {
    const int g = blockIdx.x;            // batch group: batches g*8 .. g*8+7
    const int tid = threadIdx.x;
    const int wave = tid >> 6;
    const int lane = tid & 63;
    const int lm = lane & 15;
    const int q  = lane >> 4;

    // resident recurrent weights: bw[ni][kt][j] = R[kt*32+q*8+j][(wave+8*ni)*16+lm]
    h8_t bw[4][8];
#pragma unroll
    for (int ni = 0; ni < 4; ++ni)
#pragma unroll
        for (int kt = 0; kt < 8; ++kt) {
            h8_t tv;
#pragma unroll
            for (int j = 0; j < 8; ++j)
                tv[j] = (f16)rk[(size_t)(kt * 32 + q * 8 + j) * GG + (wave + 8 * ni) * 16 + lm];
            bw[ni][kt] = tv;
        }

    __shared__ __align__(16) f16 hb[2][16][264];   // rows 8..15 stay zero (M pad)
    f16* h0 = &hb[0][0][0];
    f16* h1 = &hb[1][0][0];
    for (int i = tid; i < 2 * 16 * 264; i += 512) ((f16*)hb)[i] = (f16)0.f;

    float cst[2][4];
#pragma unroll
    for (int ni = 0; ni < 2; ++ni)
#pragma unroll
        for (int r = 0; r < 4; ++r) cst[ni][r] = 0.f;

    // per-thread xz base (linear layout): value(r,ni,t) at
    //   xz[((g*8 + q*4 + r)*1024 + t)*512 + (wave + 8*ni)*16 + lm]
    // only valid/used for q < 2 (batch rows 0..7)
    const ushort_t* xzb = xz + (size_t)(g * 8 + q * 4) * 1024 * 512 + (size_t)wave * 16 + lm;

    // prefetch xz for t=0,1
    ushort_t pf0[16], pf1[16];
    if (q < 2) {
#pragma unroll
        for (int r = 0; r < 4; ++r)
#pragma unroll
            for (int ni = 0; ni < 4; ++ni) {
                pf0[ni * 4 + r] = xzb[(size_t)r * 524288 + 0 * 512 + ni * 128];
                pf1[ni * 4 + r] = xzb[(size_t)r * 524288 + 1 * 512 + ni * 128];
            }
    }
    __syncthreads();

#pragma unroll 1
    for (int t = 0; t < TT; t += 2) {
        STEP(t,     pf0, h0, h1);
        STEP(t + 1, pf1, h1, h0);
    }

    // final dense: out[b] = h_final @ dense_w + db
    __shared__ float hf[8][256];
    if (q < 2) {
#pragma unroll
        for (int ni = 0; ni < 2; ++ni)
#pragma unroll
            for (int r = 0; r < 4; ++r)
                hf[q * 4 + r][(wave + 8 * ni) * 16 + lm] = cst[ni][r];
    }
    __syncthreads();
    if (tid < 80) {
        const int bi = tid / 10, o = tid % 10;
        float acc = db[o];
#pragma unroll 8
        for (int cc = 0; cc < CC; ++cc) acc = fmaf(hf[bi][cc], dw[cc * 10 + o], acc);
        out[(g * 8 + bi) * 10 + o] = acc;
    }
}

// ---- guard ----
__global__ void ws_too_small(float* out, float wssz) {
    int i = blockIdx.x * 256 + threadIdx.x;
    if (i < BB * 10) out[i] = (i == 0) ? wssz : 0.f;
}

extern "C" void kernel_launch(void* const* d_in, const int* in_sizes, int n_in,
                              void* d_out, int out_size, void* d_ws, size_t ws_size,
                              hipStream_t stream) {
    const float* x   = (const float*)d_in[0];
    const float* kin = (const float*)d_in[1];
    const float* rk  = (const float*)d_in[2];
    const float* rb  = (const float*)d_in[3];
    const float* dw  = (const float*)d_in[4];
    const float* db  = (const float*)d_in[5];
    float* out = (float*)d_out;

    const size_t xz_bytes = (size_t)BB * TT * GG * 2;   // 268,435,456
    const size_t kt_bytes = (size_t)GG * II * 2;        // 131,072
    if (ws_size < xz_bytes + kt_bytes) {
        ws_too_small<<<10, 256, 0, stream>>>(out, (float)ws_size);
        return;
    }

    ushort_t* xz = (ushort_t*)d_ws;
    f16* kt = (f16*)((char*)d_ws + xz_bytes);

    kt_transpose<<<256, 256, 0, stream>>>(kin, kt);
    gemm_xz<<<dim3(4, 2048), 256, 0, stream>>>(x, kt, rb, xz);
    janet_rec<<<32, 512, 0, stream>>>(rk, dw, db, xz, out);
}

// Round 4
// 1679.410 us; speedup vs baseline: 1.6951x; 1.0321x over previous
//
#include <hip/hip_runtime.h>

#define BB 256
#define TT 1024
#define II 128
#define GG 512   // 2C
#define CC 256
#define L2E 1.44269504f

typedef _Float16 f16;
typedef _Float16 h8_t __attribute__((ext_vector_type(8)));
typedef float f4_t __attribute__((ext_vector_type(4)));
typedef unsigned short ushort_t;

static __device__ __forceinline__ float fast_rcp(float x) {
#if __has_builtin(__builtin_amdgcn_rcpf)
    return __builtin_amdgcn_rcpf(x);
#else
    return 1.f / x;
#endif
}
static __device__ __forceinline__ float fast_exp2(float x) {
#if __has_builtin(__builtin_amdgcn_exp2f)
    return __builtin_amdgcn_exp2f(x);
#else
    return exp2f(x);
#endif
}

// ---- kernel 1: Kt[n][k] = f16(kernel[k][n])  (128x512 -> 512x128) ----
__global__ void kt_transpose(const float* __restrict__ kin, f16* __restrict__ kt) {
    int idx = blockIdx.x * 256 + threadIdx.x;   // 65536 total
    int k = idx >> 9;
    int n = idx & 511;
    kt[n * II + k] = (f16)kin[k * GG + n];
}

// ---- kernel 2: xzT[t][b][512] = f16( (x@K + bias) * s_col ), s = L2E (f) / 2*L2E (g) ----
// m' = t*256 + b. A-row m' -> x[b][t][:], b = m'&255, t = m'>>8. Stores stay linear in m'.
__global__ __launch_bounds__(256)
void gemm_xz(const float* __restrict__ x, const f16* __restrict__ kt,
             const float* __restrict__ bias, ushort_t* __restrict__ xz) {
    const int  ntile = blockIdx.x;   // 0..3   (128 cols)
    const long mtile = blockIdx.y;   // 0..2047 (128 rows of m')
    const int wave = threadIdx.x >> 6;
    const int lane = threadIdx.x & 63;
    const int wm = (wave & 1) * 64;
    const int wn = (wave >> 1) * 64;
    const int lm = lane & 15;
    const int q  = lane >> 4;

    f4_t acc[4][4];
#pragma unroll
    for (int mi = 0; mi < 4; ++mi)
#pragma unroll
        for (int ni = 0; ni < 4; ++ni)
            acc[mi][ni] = (f4_t){0.f, 0.f, 0.f, 0.f};

#pragma unroll
    for (int kc = 0; kc < 4; ++kc) {
        h8_t a[4], bf[4];
#pragma unroll
        for (int mi = 0; mi < 4; ++mi) {
            const int rowm = (int)(mtile * 128) + wm + mi * 16 + lm;   // m'
            const int b  = rowm & 255;
            const int tt = rowm >> 8;
            const float* ap = x + (size_t)b * (TT * II) + (size_t)tt * II + kc * 32 + q * 8;
            f4_t p0 = *(const f4_t*)ap;
            f4_t p1 = *(const f4_t*)(ap + 4);
            h8_t tv;
            tv[0] = (f16)p0[0]; tv[1] = (f16)p0[1]; tv[2] = (f16)p0[2]; tv[3] = (f16)p0[3];
            tv[4] = (f16)p1[0]; tv[5] = (f16)p1[1]; tv[6] = (f16)p1[2]; tv[7] = (f16)p1[3];
            a[mi] = tv;
        }
#pragma unroll
        for (int ni = 0; ni < 4; ++ni) {
            const f16* bp = kt + (size_t)(ntile * 128 + wn + ni * 16 + lm) * II + kc * 32 + q * 8;
            bf[ni] = *(const h8_t*)bp;
        }
#pragma unroll
        for (int mi = 0; mi < 4; ++mi)
#pragma unroll
            for (int ni = 0; ni < 4; ++ni)
                acc[mi][ni] = __builtin_amdgcn_mfma_f32_16x16x32_f16(a[mi], bf[ni], acc[mi][ni], 0, 0, 0);
    }

    // epilogue: C/D layout col=lane&15, row=(lane>>4)*4+reg (m89), linear m' store, exp2 pre-scale
#pragma unroll
    for (int mi = 0; mi < 4; ++mi) {
#pragma unroll
        for (int ni = 0; ni < 4; ++ni) {
            const int col = ntile * 128 + wn + ni * 16 + lm;
            const float bv = bias[col];
            const float s  = (col < CC) ? L2E : (2.0f * L2E);
#pragma unroll
            for (int r = 0; r < 4; ++r) {
                const size_t rowm = (size_t)(mtile * 128 + wm + mi * 16 + q * 4 + r);
                f16 hv = (f16)((acc[mi][ni][r] + bv) * s);
                xz[rowm * GG + col] = *(ushort_t*)&hv;
            }
        }
    }
}

// ---- kernel 3: MFMA recurrence. 16 WGs x 512 thr, 16 REAL batches per WG (no pad). ----
// Wave w owns n-tiles {w, w+8, w+16, w+24}: f-tiles (ni 0,1) pair with g-tiles (ni 2,3)
// in the same lane/reg. R resident (pre-scaled by L2E / 2*L2E): bw[4][8] = 128 VGPRs.
// h ping-pongs via double-buffered LDS; xzT prefetched 2 steps ahead through per-thread
// pointers with all-immediate offsets. In-loop barrier is raw (lgkmcnt only) so global
// prefetch stays in flight across steps.
#define STEP(T, PF, PP, HRD, HWR) do {                                               \
    h8_t af[8];                                                                      \
    _Pragma("unroll") for (int kt = 0; kt < 8; ++kt)                                 \
        af[kt] = *(const h8_t*)((HRD) + lm * 264 + kt * 32 + q * 8);                 \
    f4_t acc[4];                                                                     \
    _Pragma("unroll") for (int ni = 0; ni < 4; ++ni) {                               \
        f4_t av;                                                                     \
        _Pragma("unroll") for (int r = 0; r < 4; ++r) {                              \
            ushort_t u = (PF)[ni * 4 + r];                                           \
            f16 hv = *(f16*)&u;                                                      \
            av[r] = (float)hv;                                                       \
        }                                                                            \
        acc[ni] = av;                                                                \
    }                                                                                \
    if ((T) + 2 < TT) {                                                              \
        _Pragma("unroll") for (int ni = 0; ni < 4; ++ni)                             \
            _Pragma("unroll") for (int r = 0; r < 4; ++r)                            \
                (PF)[ni * 4 + r] = (PP)[r * 512 + ni * 128];                         \
        (PP) += 2 * 131072;                                                          \
    }                                                                                \
    _Pragma("unroll") for (int kt = 0; kt < 8; ++kt)                                 \
        _Pragma("unroll") for (int ni = 0; ni < 4; ++ni)                             \
            acc[ni] = __builtin_amdgcn_mfma_f32_16x16x32_f16(af[kt], bw[ni][kt], acc[ni], 0, 0, 0); \
    _Pragma("unroll") for (int ni = 0; ni < 2; ++ni)                                 \
        _Pragma("unroll") for (int r = 0; r < 4; ++r) {                              \
            float zf = acc[ni][r];                                                   \
            float zg = acc[ni + 2][r];                                               \
            float ef = fast_exp2(-zf);                                               \
            float eg = fast_exp2(-fabsf(zg));                                        \
            float t1 = (zg < 0.f) ? -ef : ef;                                        \
            float cv = cst[ni][r];                                                   \
            float num = fmaf(cv, eg, cv) + fmaf(-t1, eg, t1);                        \
            float den = (1.f + ef) * (1.f + eg);                                     \
            cst[ni][r] = num * fast_rcp(den);                                        \
        }                                                                            \
    _Pragma("unroll") for (int ni = 0; ni < 2; ++ni)                                 \
        _Pragma("unroll") for (int r = 0; r < 4; ++r)                                \
            (HWR)[(q * 4 + r) * 264 + (wave + 8 * ni) * 16 + lm] = (f16)cst[ni][r];  \
    asm volatile("s_waitcnt lgkmcnt(0)\n\ts_barrier" ::: "memory");                  \
} while (0)

__global__ __launch_bounds__(512, 2)
void janet_rec(const float* __restrict__ rk, const float* __restrict__ dw,
               const float* __restrict__ db, const ushort_t* __restrict__ xz,
               float* __restrict__ out) {
    const int g = blockIdx.x;            // batch group: batches g*16 .. g*16+15
    const int tid = threadIdx.x;
    const int wave = tid >> 6;
    const int lane = tid & 63;
    const int lm = lane & 15;
    const int q  = lane >> 4;

    // resident pre-scaled recurrent weights: bw[ni][kt][j] = s * R[kt*32+q*8+j][(wave+8*ni)*16+lm]
    h8_t bw[4][8];
#pragma unroll
    for (int ni = 0; ni < 4; ++ni) {
        const float s = (ni < 2) ? L2E : (2.0f * L2E);
#pragma unroll
        for (int kt = 0; kt < 8; ++kt) {
            h8_t tv;
#pragma unroll
            for (int j = 0; j < 8; ++j)
                tv[j] = (f16)(s * rk[(size_t)(kt * 32 + q * 8 + j) * GG + (wave + 8 * ni) * 16 + lm]);
            bw[ni][kt] = tv;
        }
    }

    __shared__ __align__(16) f16 hb[2][16][264];
    f16* h0 = &hb[0][0][0];
    f16* h1 = &hb[1][0][0];
    for (int i = tid; i < 2 * 16 * 264; i += 512) ((f16*)hb)[i] = (f16)0.f;

    float cst[2][4];
#pragma unroll
    for (int ni = 0; ni < 2; ++ni)
#pragma unroll
        for (int r = 0; r < 4; ++r) cst[ni][r] = 0.f;

    // per-thread xzT base (t-major): value(t, row=q*4+r, col=(wave+8*ni)*16+lm) at
    //   base(t)[r*512 + ni*128],  base(t) = xz + (t*256 + g*16 + q*4)*512 + wave*16 + lm
    // all 16 in-step offsets are compile-time immediates (< 4096 B).
    const ushort_t* pb = xz + ((size_t)g * 16 + q * 4) * 512 + wave * 16 + lm;
    const ushort_t* p1b = pb + 131072;          // t=1
    const ushort_t* p0 = pb + 2 * 131072;       // refill source for pf0 (t=2,4,...)
    const ushort_t* p1 = pb + 3 * 131072;       // refill source for pf1 (t=3,5,...)

    ushort_t pf0[16], pf1[16];
#pragma unroll
    for (int ni = 0; ni < 4; ++ni)
#pragma unroll
        for (int r = 0; r < 4; ++r) {
            pf0[ni * 4 + r] = pb[r * 512 + ni * 128];
            pf1[ni * 4 + r] = p1b[r * 512 + ni * 128];
        }
    __syncthreads();

#pragma unroll 1
    for (int t = 0; t < TT; t += 2) {
        STEP(t,     pf0, p0, h0, h1);
        STEP(t + 1, pf1, p1, h1, h0);
    }

    // final dense: out[b] = h_final @ dense_w + db
    __shared__ float hf[16][256];
#pragma unroll
    for (int ni = 0; ni < 2; ++ni)
#pragma unroll
        for (int r = 0; r < 4; ++r)
            hf[q * 4 + r][(wave + 8 * ni) * 16 + lm] = cst[ni][r];
    __syncthreads();
    if (tid < 160) {
        const int bi = tid / 10, o = tid % 10;
        float acc = db[o];
#pragma unroll 8
        for (int cc = 0; cc < CC; ++cc) acc = fmaf(hf[bi][cc], dw[cc * 10 + o], acc);
        out[(g * 16 + bi) * 10 + o] = acc;
    }
}

// ---- guard ----
__global__ void ws_too_small(float* out, float wssz) {
    int i = blockIdx.x * 256 + threadIdx.x;
    if (i < BB * 10) out[i] = (i == 0) ? wssz : 0.f;
}

extern "C" void kernel_launch(void* const* d_in, const int* in_sizes, int n_in,
                              void* d_out, int out_size, void* d_ws, size_t ws_size,
                              hipStream_t stream) {
    const float* x   = (const float*)d_in[0];
    const float* kin = (const float*)d_in[1];
    const float* rk  = (const float*)d_in[2];
    const float* rb  = (const float*)d_in[3];
    const float* dw  = (const float*)d_in[4];
    const float* db  = (const float*)d_in[5];
    float* out = (float*)d_out;

    const size_t xz_bytes = (size_t)BB * TT * GG * 2;   // 268,435,456
    const size_t kt_bytes = (size_t)GG * II * 2;        // 131,072
    if (ws_size < xz_bytes + kt_bytes) {
        ws_too_small<<<10, 256, 0, stream>>>(out, (float)ws_size);
        return;
    }

    ushort_t* xz = (ushort_t*)d_ws;
    f16* kt = (f16*)((char*)d_ws + xz_bytes);

    kt_transpose<<<256, 256, 0, stream>>>(kin, kt);
    gemm_xz<<<dim3(4, 2048), 256, 0, stream>>>(x, kt, rb, xz);
    janet_rec<<<16, 512, 0, stream>>>(rk, dw, db, xz, out);
}